// Round 4
// baseline (396.225 us; speedup 1.0000x reference)
//
#include <hip/hip_runtime.h>
#include <hip/hip_bf16.h>
#include <stdint.h>
#include <stddef.h>

// Causal single-head attention, B=4 S=2048 D=1024. fp32 in/out; bf16 MFMA inside.
// R4: 256x256 macro-tile, 512 threads (8 waves), wave-tile 128x64 (8x4 of
// 16x16x32 MFMA), BK=64. Rationale: dispatch time tracked block-iters/CU
// (~3k cyc each) in R2/R3; quadruple FLOP per block-iter.

typedef __hip_bfloat16 bf16;
typedef short short8 __attribute__((ext_vector_type(8)));
typedef short short4v __attribute__((ext_vector_type(4)));
typedef float f32x4 __attribute__((ext_vector_type(4)));

#define BM 256
#define BN 256
#define BK 64

__device__ __forceinline__ void async_ld16(void* lds, const void* g) {
  __builtin_amdgcn_global_load_lds(
      (const __attribute__((address_space(1))) unsigned int*)g,
      (__attribute__((address_space(3))) unsigned int*)lds, 16, 0, 0);
}

__device__ __forceinline__ void cstore(float* p, float v) { *p = v; }
__device__ __forceinline__ void cstore(bf16* p, float v) { *p = __float2bfloat16(v); }

// fp32 -> bf16 downcast, 4 elems/thread
__global__ __launch_bounds__(256)
void f2b(const float* __restrict__ s, bf16* __restrict__ d, int n) {
  const int i = (blockIdx.x * 256 + threadIdx.x) * 4;
  if (i >= n) return;
  const float4 v = *(const float4*)(s + i);
  bf16 t[4] = {__float2bfloat16(v.x), __float2bfloat16(v.y),
               __float2bfloat16(v.z), __float2bfloat16(v.w)};
  *(short4v*)(d + i) = *(short4v*)t;
}

// three weight matrices -> contiguous bf16 block, one dispatch
__global__ __launch_bounds__(256)
void f2b3(const float* __restrict__ a, const float* __restrict__ b,
          const float* __restrict__ c, bf16* __restrict__ d, int n) {
  const float* s = (blockIdx.y == 0) ? a : (blockIdx.y == 1) ? b : c;
  const int i = (blockIdx.x * 256 + threadIdx.x) * 4;
  if (i >= n) return;
  const float4 v = *(const float4*)(s + i);
  bf16 t[4] = {__float2bfloat16(v.x), __float2bfloat16(v.y),
               __float2bfloat16(v.z), __float2bfloat16(v.w)};
  *(short4v*)(d + (size_t)blockIdx.y * n + i) = *(short4v*)t;
}

// C[M,N] = A[M,K] * B[N,K]^T (both K-contiguous), bf16 in, CT out.
// 256x256 tile, 8 waves. Wave w stages k-chunk w (8 bf16) for 4 row-quarters
// of A and B (8 global_load_lds x 16B each). Wave-grid 2x4: wave covers
// 128 rows x 64 cols = 8x4 MFMA tiles; frag reuse 8x (B) / 4x (A).
template <typename CT>
__global__ __launch_bounds__(512, 2)
void gemm_bt(const bf16* __restrict__ A, const bf16* __restrict__ B,
             CT* __restrict__ C, int lda, int ldb, int ldc, int K,
             long sA, long sB, long sC, float scale,
             int causal_skip, int causal_klimit) {
  int by = blockIdx.y, bx = blockIdx.x;
  if (causal_klimit) by = gridDim.y - 1 - by;  // long-K blocks dispatch first
  if (causal_skip && bx > by) return;          // tile fully above diagonal

  __shared__ short8 As[8 * 256];  // 32 KB: [chunk 0..7][row 0..255]
  __shared__ short8 Bs[8 * 256];  // 32 KB

  const int tid = threadIdx.x;
  const int wave = tid >> 6, lane = tid & 63;
  const int wm = wave >> 2, wn = wave & 3;  // 2x4 wave grid; tile 128x64
  const int l15 = lane & 15, q4 = lane >> 4;
  const int bm0 = by * BM, bn0 = bx * BN;

  const bf16* Az = A + (long)blockIdx.z * sA;
  const bf16* Bz = B + (long)blockIdx.z * sB;
  CT* Cz = C + (long)blockIdx.z * sC;

  // staging pointers: wave stages chunk `wave`, rows lane+64t
  const bf16* ap = Az + (size_t)(bm0 + lane) * lda + wave * 8;
  const bf16* bp = Bz + (size_t)(bn0 + lane) * ldb + wave * 8;
  short8* dA = &As[wave * 256 + lane];
  short8* dB = &Bs[wave * 256 + lane];
  const size_t la64 = (size_t)64 * lda, lb64 = (size_t)64 * ldb;

  const int Ke = causal_klimit ? min(K, (by + 1) * BM) : K;

  f32x4 acc[8][4] = {};

  for (int k0 = 0; k0 < Ke; k0 += BK) {
    __syncthreads();  // prior iter's LDS reads done
#pragma unroll
    for (int t = 0; t < 4; t++) {
      async_ld16(dA + t * 64, ap + t * la64 + k0);
      async_ld16(dB + t * 64, bp + t * lb64 + k0);
    }
    __syncthreads();  // compiler drains vmcnt before barrier

#pragma unroll
    for (int s = 0; s < 2; s++) {
      const int ch = (s * 4 + q4) * 256;
      short8 af[8], bfr[4];
#pragma unroll
      for (int i = 0; i < 8; i++)
        af[i] = As[ch + wm * 128 + i * 16 + l15];
#pragma unroll
      for (int j = 0; j < 4; j++)
        bfr[j] = Bs[ch + wn * 64 + j * 16 + l15];
#pragma unroll
      for (int i = 0; i < 8; i++)
#pragma unroll
        for (int j = 0; j < 4; j++)
          acc[i][j] = __builtin_amdgcn_mfma_f32_16x16x32_bf16(af[i], bfr[j], acc[i][j], 0, 0, 0);
    }
  }

  // epilogue: C/D layout col=lane&15, row=(lane>>4)*4+reg  [m89/m91 verified]
#pragma unroll
  for (int i = 0; i < 8; i++) {
#pragma unroll
    for (int j = 0; j < 4; j++) {
#pragma unroll
      for (int r = 0; r < 4; r++) {
        const int row = bm0 + wm * 128 + i * 16 + q4 * 4 + r;
        const int col = bn0 + wn * 64 + j * 16 + l15;
        cstore(&Cz[(size_t)row * ldc + col], acc[i][j][r] * scale);
      }
    }
  }
}

// Single-pass register softmax over the causal prefix; one 256-thr block per
// (q,b) row. Zeros above the diagonal so the PV GEMM needs no masking.
__global__ __launch_bounds__(256)
void softmax_rows(const bf16* __restrict__ Sc, bf16* __restrict__ P, int S) {
  const int q = blockIdx.x, b = blockIdx.y;
  const short8* srow = (const short8*)(Sc + ((size_t)b * S + q) * S);
  short8* prow = (short8*)(P + ((size_t)b * S + q) * S);
  const int len = q + 1;
  const int tid = threadIdx.x;
  const int wave = tid >> 6, lane = tid & 63;
  __shared__ float red[10];

  const short8 raw = srow[tid];
  float v[8];
#pragma unroll
  for (int j = 0; j < 8; j++) {
    const int k = tid * 8 + j;
    const float f = __bfloat162float(((const bf16*)&raw)[j]);
    v[j] = (k < len) ? f : -1e30f;
  }

  float m = v[0];
#pragma unroll
  for (int j = 1; j < 8; j++) m = fmaxf(m, v[j]);
#pragma unroll
  for (int o = 32; o; o >>= 1) m = fmaxf(m, __shfl_down(m, o));
  if (lane == 0) red[wave] = m;
  __syncthreads();
  if (tid == 0) red[8] = fmaxf(fmaxf(red[0], red[1]), fmaxf(red[2], red[3]));
  __syncthreads();
  const float M = red[8];

  float e[8], s = 0.f;
#pragma unroll
  for (int j = 0; j < 8; j++) { e[j] = __expf(v[j] - M); s += e[j]; }
#pragma unroll
  for (int o = 32; o; o >>= 1) s += __shfl_down(s, o);
  if (lane == 0) red[4 + wave] = s;
  __syncthreads();
  if (tid == 0) red[9] = red[4] + red[5] + red[6] + red[7];
  __syncthreads();
  const float inv = 1.f / red[9];

  short8 outp;
#pragma unroll
  for (int j = 0; j < 8; j++) {
    const int k = tid * 8 + j;
    ((bf16*)&outp)[j] = __float2bfloat16((k < len) ? e[j] * inv : 0.f);
  }
  prow[tid] = outp;
}

extern "C" void kernel_launch(void* const* d_in, const int* in_sizes, int n_in,
                              void* d_out, int out_size, void* d_ws, size_t ws_size,
                              hipStream_t stream) {
  const float* x  = (const float*)d_in[0];
  const float* Wq = (const float*)d_in[1];
  const float* Wk = (const float*)d_in[2];
  const float* Wv = (const float*)d_in[3];
  float* out = (float*)d_out;

  const int Bb = 4, S = 2048, D = 1024, MS = Bb * S;  // MS = 8192

  // ws layout; P aliases dead xb/W/Q region (consumed before softmax).
  char* ws = (char*)d_ws;
  bf16* xb = (bf16*)ws;                                          // 16.78 MB
  bf16* wb = (bf16*)(ws + (size_t)MS * D * 2);                   // 6.3 MB
  bf16* Q  = (bf16*)(ws + (size_t)MS * D * 2 + 3u * D * D * 2);  // 16.78 MB
  bf16* Kp = Q + (size_t)MS * D;                                 // 16.78 MB
  bf16* VT = Kp + (size_t)MS * D;                                // 16.78 MB [D,MS]
  bf16* Sc = VT + (size_t)MS * D;                                // 33.55 MB [B,S,S]
  bf16* P  = (bf16*)ws;                                          // aliases xb/W/Q

  dim3 blk(512);
  dim3 blk256(256);

  f2b<<<dim3(MS * D / 4 / 256), blk256, 0, stream>>>(x, xb, MS * D);
  f2b3<<<dim3(D * D / 4 / 256, 3), blk256, 0, stream>>>(Wq, Wk, Wv, wb, D * D);

  // [Q;K] = xb @ {Wq,Wk}^T  (z=2)
  gemm_bt<bf16><<<dim3(D / BN, MS / BM, 2), blk, 0, stream>>>(
      xb, wb, Q, D, D, D, D, 0, (long)D * D, (long)MS * D, 1.f, 0, 0);
  // VT = Wv @ xb^T  [1024, 8192]
  gemm_bt<bf16><<<dim3(MS / BN, D / BM, 1), blk, 0, stream>>>(
      wb + 2u * D * D, xb, VT, D, D, MS, D, 0, 0, 0, 1.f, 0, 0);
  // Sc = (Q K^T)/32 per batch, lower-triangular tiles only
  gemm_bt<bf16><<<dim3(S / BN, S / BM, Bb), blk, 0, stream>>>(
      Q, Kp, Sc, D, D, S, D,
      (long)S * D, (long)S * D, (long)S * S, 0.03125f, 1, 0);
  // P = row-softmax(Sc)
  softmax_rows<<<dim3(S, Bb), blk256, 0, stream>>>(Sc, P, S);
  // out = P @ V  (B = VT batch slice, K clipped at diagonal)
  gemm_bt<float><<<dim3(D / BN, S / BM, Bb), blk, 0, stream>>>(
      P, VT, out, S, MS, D, S,
      (long)S * S, (long)S, (long)S * D, 1.f, 0, 1);
}

// Round 5
// 360.389 us; speedup vs baseline: 1.0994x; 1.0994x over previous
//
#include <hip/hip_runtime.h>
#include <hip/hip_bf16.h>
#include <stdint.h>
#include <stddef.h>

// Causal single-head attention, B=4 S=2048 D=1024. fp32 in/out; bf16 MFMA inside.
// R5: back to 128x128/BK=32 (R2 shape), + double-buffered LDS with issue-after-
// barrier (hides global->LDS latency behind the MFMA phase; the vmcnt(0) drain
// at each barrier now waits on loads issued one full compute-phase earlier),
// one barrier/iter, __launch_bounds__(256,4) for 4 resident blocks/CU.

typedef __hip_bfloat16 bf16;
typedef short short8 __attribute__((ext_vector_type(8)));
typedef short short4v __attribute__((ext_vector_type(4)));
typedef float f32x4 __attribute__((ext_vector_type(4)));

#define BM 128
#define BN 128
#define BK 32

__device__ __forceinline__ void async_ld16(void* lds, const void* g) {
  __builtin_amdgcn_global_load_lds(
      (const __attribute__((address_space(1))) unsigned int*)g,
      (__attribute__((address_space(3))) unsigned int*)lds, 16, 0, 0);
}

__device__ __forceinline__ void cstore(float* p, float v) { *p = v; }
__device__ __forceinline__ void cstore(bf16* p, float v) { *p = __float2bfloat16(v); }

// fp32 -> bf16 downcast, 4 elems/thread
__global__ __launch_bounds__(256)
void f2b(const float* __restrict__ s, bf16* __restrict__ d, int n) {
  const int i = (blockIdx.x * 256 + threadIdx.x) * 4;
  if (i >= n) return;
  const float4 v = *(const float4*)(s + i);
  bf16 t[4] = {__float2bfloat16(v.x), __float2bfloat16(v.y),
               __float2bfloat16(v.z), __float2bfloat16(v.w)};
  *(short4v*)(d + i) = *(short4v*)t;
}

// three weight matrices -> contiguous bf16 block, one dispatch
__global__ __launch_bounds__(256)
void f2b3(const float* __restrict__ a, const float* __restrict__ b,
          const float* __restrict__ c, bf16* __restrict__ d, int n) {
  const float* s = (blockIdx.y == 0) ? a : (blockIdx.y == 1) ? b : c;
  const int i = (blockIdx.x * 256 + threadIdx.x) * 4;
  if (i >= n) return;
  const float4 v = *(const float4*)(s + i);
  bf16 t[4] = {__float2bfloat16(v.x), __float2bfloat16(v.y),
               __float2bfloat16(v.z), __float2bfloat16(v.w)};
  *(short4v*)(d + (size_t)blockIdx.y * n + i) = *(short4v*)t;
}

// C[M,N] = A[M,K] * B[N,K]^T (both K-contiguous), bf16 in, CT out.
// 128x128 tile, 4 waves (2x2 grid of 64x64 wave-tiles), BK=32, double-buffered
// LDS. Wave w stages k-chunk w (8 bf16) for rows {lane, lane+64} of A and B.
template <typename CT>
__global__ __launch_bounds__(256, 4)
void gemm_bt(const bf16* __restrict__ A, const bf16* __restrict__ B,
             CT* __restrict__ C, int lda, int ldb, int ldc, int K,
             long sA, long sB, long sC, float scale,
             int causal_skip, int causal_klimit) {
  int by = blockIdx.y, bx = blockIdx.x;
  if (causal_klimit) by = gridDim.y - 1 - by;  // long-K blocks dispatch first
  if (causal_skip && bx > by) return;          // tile fully above diagonal

  __shared__ short8 As[2][4 * 128];  // 2 x 8 KB
  __shared__ short8 Bs[2][4 * 128];  // 2 x 8 KB

  const int tid = threadIdx.x;
  const int wave = tid >> 6, lane = tid & 63;
  const int wm = wave >> 1, wn = wave & 1;  // 2x2 wave grid, 64x64 each
  const int l15 = lane & 15, q4 = lane >> 4;
  const int bm0 = by * BM, bn0 = bx * BN;

  const bf16* Az = A + (long)blockIdx.z * sA;
  const bf16* Bz = B + (long)blockIdx.z * sB;
  CT* Cz = C + (long)blockIdx.z * sC;

  // wave w stages k-chunk q=w (8 bf16) for rows {lane, lane+64}
  const bf16* ap0 = Az + (size_t)(bm0 + lane) * lda + wave * 8;
  const bf16* ap1 = ap0 + (size_t)64 * lda;
  const bf16* bp0 = Bz + (size_t)(bn0 + lane) * ldb + wave * 8;
  const bf16* bp1 = bp0 + (size_t)64 * ldb;
  const int ldst = wave * 128 + lane;

  const int Ke = causal_klimit ? min(K, (by + 1) * BM) : K;

  f32x4 acc[4][4] = {};

  // prologue: stage k0=0 into buffer 0 (its drain is the only cold one)
  async_ld16(&As[0][ldst], ap0);
  async_ld16(&As[0][ldst + 64], ap1);
  async_ld16(&Bs[0][ldst], bp0);
  async_ld16(&Bs[0][ldst + 64], bp1);

  int ib = 0;
  for (int k0 = 0; k0 < Ke; k0 += BK, ib ^= 1) {
    // Barrier: (a) all waves done reading buf[ib^1] (iter k-1's compute), so
    // it may be overwritten; (b) per-wave vmcnt(0) drain covers the loads
    // into buf[ib] issued one full compute-phase ago.
    __syncthreads();
    const int kn = k0 + BK;
    if (kn < Ke) {
      async_ld16(&As[ib ^ 1][ldst], ap0 + kn);
      async_ld16(&As[ib ^ 1][ldst + 64], ap1 + kn);
      async_ld16(&Bs[ib ^ 1][ldst], bp0 + kn);
      async_ld16(&Bs[ib ^ 1][ldst + 64], bp1 + kn);
    }

    short8 af[4], bfr[4];
#pragma unroll
    for (int i = 0; i < 4; i++)
      af[i] = As[ib][q4 * 128 + wm * 64 + i * 16 + l15];
#pragma unroll
    for (int j = 0; j < 4; j++)
      bfr[j] = Bs[ib][q4 * 128 + wn * 64 + j * 16 + l15];
#pragma unroll
    for (int i = 0; i < 4; i++)
#pragma unroll
      for (int j = 0; j < 4; j++)
        acc[i][j] = __builtin_amdgcn_mfma_f32_16x16x32_bf16(af[i], bfr[j], acc[i][j], 0, 0, 0);
  }

  // epilogue: C/D layout col=lane&15, row=(lane>>4)*4+reg  [m89/m91 verified]
#pragma unroll
  for (int i = 0; i < 4; i++) {
#pragma unroll
    for (int j = 0; j < 4; j++) {
#pragma unroll
      for (int r = 0; r < 4; r++) {
        const int row = bm0 + wm * 64 + i * 16 + q4 * 4 + r;
        const int col = bn0 + wn * 64 + j * 16 + l15;
        cstore(&Cz[(size_t)row * ldc + col], acc[i][j][r] * scale);
      }
    }
  }
}

// Single-pass register softmax over the causal prefix; one 256-thr block per
// (q,b) row. Zeros above the diagonal so the PV GEMM needs no masking.
__global__ __launch_bounds__(256)
void softmax_rows(const bf16* __restrict__ Sc, bf16* __restrict__ P, int S) {
  const int q = blockIdx.x, b = blockIdx.y;
  const short8* srow = (const short8*)(Sc + ((size_t)b * S + q) * S);
  short8* prow = (short8*)(P + ((size_t)b * S + q) * S);
  const int len = q + 1;
  const int tid = threadIdx.x;
  const int wave = tid >> 6, lane = tid & 63;
  __shared__ float red[10];

  const short8 raw = srow[tid];
  float v[8];
#pragma unroll
  for (int j = 0; j < 8; j++) {
    const int k = tid * 8 + j;
    const float f = __bfloat162float(((const bf16*)&raw)[j]);
    v[j] = (k < len) ? f : -1e30f;
  }

  float m = v[0];
#pragma unroll
  for (int j = 1; j < 8; j++) m = fmaxf(m, v[j]);
#pragma unroll
  for (int o = 32; o; o >>= 1) m = fmaxf(m, __shfl_down(m, o));
  if (lane == 0) red[wave] = m;
  __syncthreads();
  if (tid == 0) red[8] = fmaxf(fmaxf(red[0], red[1]), fmaxf(red[2], red[3]));
  __syncthreads();
  const float M = red[8];

  float e[8], s = 0.f;
#pragma unroll
  for (int j = 0; j < 8; j++) { e[j] = __expf(v[j] - M); s += e[j]; }
#pragma unroll
  for (int o = 32; o; o >>= 1) s += __shfl_down(s, o);
  if (lane == 0) red[4 + wave] = s;
  __syncthreads();
  if (tid == 0) red[9] = red[4] + red[5] + red[6] + red[7];
  __syncthreads();
  const float inv = 1.f / red[9];

  short8 outp;
#pragma unroll
  for (int j = 0; j < 8; j++) {
    const int k = tid * 8 + j;
    ((bf16*)&outp)[j] = __float2bfloat16((k < len) ? e[j] * inv : 0.f);
  }
  prow[tid] = outp;
}

extern "C" void kernel_launch(void* const* d_in, const int* in_sizes, int n_in,
                              void* d_out, int out_size, void* d_ws, size_t ws_size,
                              hipStream_t stream) {
  const float* x  = (const float*)d_in[0];
  const float* Wq = (const float*)d_in[1];
  const float* Wk = (const float*)d_in[2];
  const float* Wv = (const float*)d_in[3];
  float* out = (float*)d_out;

  const int Bb = 4, S = 2048, D = 1024, MS = Bb * S;  // MS = 8192

  // ws layout; P aliases dead xb/W/Q region (consumed before softmax).
  char* ws = (char*)d_ws;
  bf16* xb = (bf16*)ws;                                          // 16.78 MB
  bf16* wb = (bf16*)(ws + (size_t)MS * D * 2);                   // 6.3 MB
  bf16* Q  = (bf16*)(ws + (size_t)MS * D * 2 + 3u * D * D * 2);  // 16.78 MB
  bf16* Kp = Q + (size_t)MS * D;                                 // 16.78 MB
  bf16* VT = Kp + (size_t)MS * D;                                // 16.78 MB [D,MS]
  bf16* Sc = VT + (size_t)MS * D;                                // 33.55 MB [B,S,S]
  bf16* P  = (bf16*)ws;                                          // aliases xb/W/Q

  dim3 blk(256);

  f2b<<<dim3(MS * D / 4 / 256), blk, 0, stream>>>(x, xb, MS * D);
  f2b3<<<dim3(D * D / 4 / 256, 3), blk, 0, stream>>>(Wq, Wk, Wv, wb, D * D);

  // [Q;K] = xb @ {Wq,Wk}^T  (z=2)
  gemm_bt<bf16><<<dim3(D / BN, MS / BM, 2), blk, 0, stream>>>(
      xb, wb, Q, D, D, D, D, 0, (long)D * D, (long)MS * D, 1.f, 0, 0);
  // VT = Wv @ xb^T  [1024, 8192]
  gemm_bt<bf16><<<dim3(MS / BN, D / BM, 1), blk, 0, stream>>>(
      wb + 2u * D * D, xb, VT, D, D, MS, D, 0, 0, 0, 1.f, 0, 0);
  // Sc = (Q K^T)/32 per batch, lower-triangular tiles only
  gemm_bt<bf16><<<dim3(S / BN, S / BM, Bb), blk, 0, stream>>>(
      Q, Kp, Sc, D, D, S, D,
      (long)S * D, (long)S * D, (long)S * S, 0.03125f, 1, 0);
  // P = row-softmax(Sc)
  softmax_rows<<<dim3(S, Bb), blk, 0, stream>>>(Sc, P, S);
  // out = P @ V  (B = VT batch slice, K clipped at diagonal)
  gemm_bt<float><<<dim3(D / BN, S / BM, Bb), blk, 0, stream>>>(
      P, VT, out, S, MS, D, S,
      (long)S * S, (long)S, (long)S * D, 1.f, 0, 1);
}

// Round 6
// 345.535 us; speedup vs baseline: 1.1467x; 1.0430x over previous
//
#include <hip/hip_runtime.h>
#include <hip/hip_bf16.h>
#include <stdint.h>
#include <stddef.h>

// Causal single-head attention, B=4 S=2048 D=1024. fp32 in/out; bf16 MFMA inside.
// R6: coalesced staging. Replace row-per-lane global_load_lds (64 cache lines
// per inst) with 8-lanes-per-row global->VGPR loads (8 lines per inst) +
// conflict-free ds_write_b128 into the SAME [k-granule][row] LDS layout the
// m97-style frag reads expect. VGPR-side double buffer: loads for iter k+1
// issued right after the post-write barrier, consumed by next iter's ds_write
// (vmcnt wait lands one full compute phase later, never drains at barrier).

typedef __hip_bfloat16 bf16;
typedef short short8 __attribute__((ext_vector_type(8)));
typedef short short4v __attribute__((ext_vector_type(4)));
typedef float f32x4 __attribute__((ext_vector_type(4)));

#define BM 128
#define BN 128
#define BK 64

__device__ __forceinline__ void cstore(float* p, float v) { *p = v; }
__device__ __forceinline__ void cstore(bf16* p, float v) { *p = __float2bfloat16(v); }

// fp32 -> bf16 downcast, 4 elems/thread
__global__ __launch_bounds__(256)
void f2b(const float* __restrict__ s, bf16* __restrict__ d, int n) {
  const int i = (blockIdx.x * 256 + threadIdx.x) * 4;
  if (i >= n) return;
  const float4 v = *(const float4*)(s + i);
  bf16 t[4] = {__float2bfloat16(v.x), __float2bfloat16(v.y),
               __float2bfloat16(v.z), __float2bfloat16(v.w)};
  *(short4v*)(d + i) = *(short4v*)t;
}

// three weight matrices -> contiguous bf16 block, one dispatch
__global__ __launch_bounds__(256)
void f2b3(const float* __restrict__ a, const float* __restrict__ b,
          const float* __restrict__ c, bf16* __restrict__ d, int n) {
  const float* s = (blockIdx.y == 0) ? a : (blockIdx.y == 1) ? b : c;
  const int i = (blockIdx.x * 256 + threadIdx.x) * 4;
  if (i >= n) return;
  const float4 v = *(const float4*)(s + i);
  bf16 t[4] = {__float2bfloat16(v.x), __float2bfloat16(v.y),
               __float2bfloat16(v.z), __float2bfloat16(v.w)};
  *(short4v*)(d + (size_t)blockIdx.y * n + i) = *(short4v*)t;
}

// C[M,N] = A[M,K] * B[N,K]^T (both K-contiguous), bf16 in, CT out.
// 128x128 tile, 4 waves (2x2 of 64x64), BK=64.
// Staging: thread t covers row (j*32 + wave*8 + (t&7)), k-granule ((t>>3)&7)
// [8 bf16 = 16 B]. One wave-inst = 8 rows x full 128 B line = 8 lines.
// LDS layout: As[granule g][row r] (16 B each) — identical to m97 frag layout.
// ds_write bank check (8-lane groups): lanes 0-7 have g fixed, rows 0-7
// consecutive -> granule index g*128+r -> bank class r%8 all distinct: clean.
template <typename CT>
__global__ __launch_bounds__(256, 3)
void gemm_bt(const bf16* __restrict__ A, const bf16* __restrict__ B,
             CT* __restrict__ C, int lda, int ldb, int ldc, int K,
             long sA, long sB, long sC, float scale,
             int causal_skip, int causal_klimit) {
  int by = blockIdx.y, bx = blockIdx.x;
  if (causal_klimit) by = gridDim.y - 1 - by;  // long-K blocks dispatch first
  if (causal_skip && bx > by) return;          // tile fully above diagonal

  __shared__ short8 As[8 * 128];  // 16 KB: [granule 0..7][row 0..127]
  __shared__ short8 Bs[8 * 128];  // 16 KB

  const int tid = threadIdx.x;
  const int wave = tid >> 6, lane = tid & 63;
  const int wm = wave >> 1, wn = wave & 1;  // 2x2 wave grid, 64x64 each
  const int l15 = lane & 15, q4 = lane >> 4;
  const int bm0 = by * BM, bn0 = bx * BN;

  const bf16* Az = A + (long)blockIdx.z * sA;
  const bf16* Bz = B + (long)blockIdx.z * sB;
  CT* Cz = C + (long)blockIdx.z * sC;

  // staging coordinates
  const int kg = (lane >> 3) & 7;      // k-granule 0..7 (16 B each)
  const int rl = wave * 8 + (lane & 7);  // row within 32-row group quarter

  const bf16* apg = Az + (size_t)(bm0 + rl) * lda + kg * 8;
  const bf16* bpg = Bz + (size_t)(bn0 + rl) * ldb + kg * 8;
  const size_t la32 = (size_t)32 * lda, lb32 = (size_t)32 * ldb;
  short8* dstA = &As[kg * 128 + rl];
  short8* dstB = &Bs[kg * 128 + rl];

  const int Ke = causal_klimit ? min(K, (by + 1) * BM) : K;

  f32x4 acc[4][4] = {};
  short8 ra[4], rb[4];

  // preload k0 = 0
#pragma unroll
  for (int j = 0; j < 4; j++) {
    ra[j] = *(const short8*)(apg + j * la32);
    rb[j] = *(const short8*)(bpg + j * lb32);
  }

  for (int k0 = 0; k0 < Ke; k0 += BK) {
    __syncthreads();  // all waves done reading LDS from prior iter
#pragma unroll
    for (int j = 0; j < 4; j++) {
      dstA[j * 32] = ra[j];   // vmcnt wait for ra/rb lands here — loads had a
      dstB[j * 32] = rb[j];   // full compute phase to complete
    }
    __syncthreads();  // staged data visible

    const int kn = k0 + BK;
    if (kn < Ke) {  // issue next iter's loads; in flight across the compute
#pragma unroll
      for (int j = 0; j < 4; j++) {
        ra[j] = *(const short8*)(apg + j * la32 + kn);
        rb[j] = *(const short8*)(bpg + j * lb32 + kn);
      }
    }

#pragma unroll
    for (int s = 0; s < 2; s++) {
      const int ch = (s * 4 + q4) * 128;
      short8 af[4], bfr[4];
#pragma unroll
      for (int i = 0; i < 4; i++)
        af[i] = As[ch + wm * 64 + i * 16 + l15];
#pragma unroll
      for (int j = 0; j < 4; j++)
        bfr[j] = Bs[ch + wn * 64 + j * 16 + l15];
#pragma unroll
      for (int i = 0; i < 4; i++)
#pragma unroll
        for (int j = 0; j < 4; j++)
          acc[i][j] = __builtin_amdgcn_mfma_f32_16x16x32_bf16(af[i], bfr[j], acc[i][j], 0, 0, 0);
    }
  }

  // epilogue: C/D layout col=lane&15, row=(lane>>4)*4+reg  [m89/m91 verified]
#pragma unroll
  for (int i = 0; i < 4; i++) {
#pragma unroll
    for (int j = 0; j < 4; j++) {
#pragma unroll
      for (int r = 0; r < 4; r++) {
        const int row = bm0 + wm * 64 + i * 16 + q4 * 4 + r;
        const int col = bn0 + wn * 64 + j * 16 + l15;
        cstore(&Cz[(size_t)row * ldc + col], acc[i][j][r] * scale);
      }
    }
  }
}

// Single-pass register softmax over the causal prefix; one 256-thr block per
// (q,b) row. Zeros above the diagonal so the PV GEMM needs no masking.
__global__ __launch_bounds__(256)
void softmax_rows(const bf16* __restrict__ Sc, bf16* __restrict__ P, int S) {
  const int q = blockIdx.x, b = blockIdx.y;
  const short8* srow = (const short8*)(Sc + ((size_t)b * S + q) * S);
  short8* prow = (short8*)(P + ((size_t)b * S + q) * S);
  const int len = q + 1;
  const int tid = threadIdx.x;
  const int wave = tid >> 6, lane = tid & 63;
  __shared__ float red[10];

  const short8 raw = srow[tid];
  float v[8];
#pragma unroll
  for (int j = 0; j < 8; j++) {
    const int k = tid * 8 + j;
    const float f = __bfloat162float(((const bf16*)&raw)[j]);
    v[j] = (k < len) ? f : -1e30f;
  }

  float m = v[0];
#pragma unroll
  for (int j = 1; j < 8; j++) m = fmaxf(m, v[j]);
#pragma unroll
  for (int o = 32; o; o >>= 1) m = fmaxf(m, __shfl_down(m, o));
  if (lane == 0) red[wave] = m;
  __syncthreads();
  if (tid == 0) red[8] = fmaxf(fmaxf(red[0], red[1]), fmaxf(red[2], red[3]));
  __syncthreads();
  const float M = red[8];

  float e[8], s = 0.f;
#pragma unroll
  for (int j = 0; j < 8; j++) { e[j] = __expf(v[j] - M); s += e[j]; }
#pragma unroll
  for (int o = 32; o; o >>= 1) s += __shfl_down(s, o);
  if (lane == 0) red[4 + wave] = s;
  __syncthreads();
  if (tid == 0) red[9] = red[4] + red[5] + red[6] + red[7];
  __syncthreads();
  const float inv = 1.f / red[9];

  short8 outp;
#pragma unroll
  for (int j = 0; j < 8; j++) {
    const int k = tid * 8 + j;
    ((bf16*)&outp)[j] = __float2bfloat16((k < len) ? e[j] * inv : 0.f);
  }
  prow[tid] = outp;
}

extern "C" void kernel_launch(void* const* d_in, const int* in_sizes, int n_in,
                              void* d_out, int out_size, void* d_ws, size_t ws_size,
                              hipStream_t stream) {
  const float* x  = (const float*)d_in[0];
  const float* Wq = (const float*)d_in[1];
  const float* Wk = (const float*)d_in[2];
  const float* Wv = (const float*)d_in[3];
  float* out = (float*)d_out;

  const int Bb = 4, S = 2048, D = 1024, MS = Bb * S;  // MS = 8192

  // ws layout; P aliases dead xb/W/Q region (consumed before softmax).
  char* ws = (char*)d_ws;
  bf16* xb = (bf16*)ws;                                          // 16.78 MB
  bf16* wb = (bf16*)(ws + (size_t)MS * D * 2);                   // 6.3 MB
  bf16* Q  = (bf16*)(ws + (size_t)MS * D * 2 + 3u * D * D * 2);  // 16.78 MB
  bf16* Kp = Q + (size_t)MS * D;                                 // 16.78 MB
  bf16* VT = Kp + (size_t)MS * D;                                // 16.78 MB [D,MS]
  bf16* Sc = VT + (size_t)MS * D;                                // 33.55 MB [B,S,S]
  bf16* P  = (bf16*)ws;                                          // aliases xb/W/Q

  dim3 blk(256);

  f2b<<<dim3(MS * D / 4 / 256), blk, 0, stream>>>(x, xb, MS * D);
  f2b3<<<dim3(D * D / 4 / 256, 3), blk, 0, stream>>>(Wq, Wk, Wv, wb, D * D);

  // [Q;K] = xb @ {Wq,Wk}^T  (z=2)
  gemm_bt<bf16><<<dim3(D / BN, MS / BM, 2), blk, 0, stream>>>(
      xb, wb, Q, D, D, D, D, 0, (long)D * D, (long)MS * D, 1.f, 0, 0);
  // VT = Wv @ xb^T  [1024, 8192]
  gemm_bt<bf16><<<dim3(MS / BN, D / BM, 1), blk, 0, stream>>>(
      wb + 2u * D * D, xb, VT, D, D, MS, D, 0, 0, 0, 1.f, 0, 0);
  // Sc = (Q K^T)/32 per batch, lower-triangular tiles only
  gemm_bt<bf16><<<dim3(S / BN, S / BM, Bb), blk, 0, stream>>>(
      Q, Kp, Sc, D, D, S, D,
      (long)S * D, (long)S * D, (long)S * S, 0.03125f, 1, 0);
  // P = row-softmax(Sc)
  softmax_rows<<<dim3(S, Bb), blk, 0, stream>>>(Sc, P, S);
  // out = P @ V  (B = VT batch slice, K clipped at diagonal)
  gemm_bt<float><<<dim3(D / BN, S / BM, Bb), blk, 0, stream>>>(
      P, VT, out, S, MS, D, S,
      (long)S * S, (long)S, (long)S * D, 1.f, 0, 1);
}

// Round 7
// 314.066 us; speedup vs baseline: 1.2616x; 1.1002x over previous
//
#include <hip/hip_runtime.h>
#include <hip/hip_bf16.h>
#include <stdint.h>
#include <stddef.h>

// Causal single-head attention, B=4 S=2048 D=1024. fp32 in/out; bf16 MFMA inside.
// R7: (a) compact triangular grid for the causal Sc GEMM (544 balanced blocks,
// no early-exit stragglers); (b) QKV fused into one GEMM over stacked weights,
// V written transposed in the epilogue (kills the separate VT dispatch);
// (c) R6 coalesced staging kept (best measured: 8 lanes/row, VGPR dbuf).

typedef __hip_bfloat16 bf16;
typedef short short8 __attribute__((ext_vector_type(8)));
typedef short short4v __attribute__((ext_vector_type(4)));
typedef float f32x4 __attribute__((ext_vector_type(4)));

#define BM 128
#define BN 128
#define BK 64
#define MSZ 8192   // B*S
#define DD 1024    // D

__device__ __forceinline__ void cstore(float* p, float v) { *p = v; }
__device__ __forceinline__ void cstore(bf16* p, float v) { *p = __float2bfloat16(v); }

// fp32 -> bf16 downcast, 4 elems/thread
__global__ __launch_bounds__(256)
void f2b(const float* __restrict__ s, bf16* __restrict__ d, int n) {
  const int i = (blockIdx.x * 256 + threadIdx.x) * 4;
  if (i >= n) return;
  const float4 v = *(const float4*)(s + i);
  bf16 t[4] = {__float2bfloat16(v.x), __float2bfloat16(v.y),
               __float2bfloat16(v.z), __float2bfloat16(v.w)};
  *(short4v*)(d + i) = *(short4v*)t;
}

// three weight matrices -> contiguous bf16 block [Wq;Wk;Wv]
__global__ __launch_bounds__(256)
void f2b3(const float* __restrict__ a, const float* __restrict__ b,
          const float* __restrict__ c, bf16* __restrict__ d, int n) {
  const float* s = (blockIdx.y == 0) ? a : (blockIdx.y == 1) ? b : c;
  const int i = (blockIdx.x * 256 + threadIdx.x) * 4;
  if (i >= n) return;
  const float4 v = *(const float4*)(s + i);
  bf16 t[4] = {__float2bfloat16(v.x), __float2bfloat16(v.y),
               __float2bfloat16(v.z), __float2bfloat16(v.w)};
  *(short4v*)(d + (size_t)blockIdx.y * n + i) = *(short4v*)t;
}

// C[M,N] = A[M,K] * B[N,K]^T (both K-contiguous), bf16 in.
// MODE 1: QKV — A=xb, B=W_all[3072,1024]; bx<16 -> Q|K contiguous rows,
//         bx>=16 -> V stored transposed into C2[D][MS].
// MODE 2: Sc — compact triangular grid: blockIdx.x = tri index (by,bx).
// MODE 3: PV — float out, K clipped at diagonal, by reversed (long-K first).
// Staging (R6): thread covers row wave*8+(lane&7), k-granule (lane>>3)&7;
// one wave-inst = 8 full 128-B lines. LDS [granule][row] = m97 frag layout.
template <int MODE, typename CT>
__global__ __launch_bounds__(256, 3)
void gemm_bt(const bf16* __restrict__ A, const bf16* __restrict__ B,
             CT* __restrict__ C, bf16* __restrict__ C2,
             int lda, int ldb, int ldc, int K,
             long sA, long sB, long sC, float scale) {
  int by, bx;
  if (MODE == 2) {
    // triangular decode: t -> (by, bx), bx <= by, 136 tiles for 16 rows
    const int t = blockIdx.x;
    by = (int)((__fsqrt_rn(8.f * (float)t + 1.f) - 1.f) * 0.5f);
    while ((by + 1) * (by + 2) / 2 <= t) by++;
    while (by * (by + 1) / 2 > t) by--;
    bx = t - by * (by + 1) / 2;
  } else if (MODE == 3) {
    by = gridDim.y - 1 - blockIdx.y;  // long-K rows dispatch first
    bx = blockIdx.x;
  } else {
    by = blockIdx.y;
    bx = blockIdx.x;
  }

  __shared__ short8 As[8 * 128];  // 16 KB: [granule 0..7][row 0..127]
  __shared__ short8 Bs[8 * 128];  // 16 KB

  const int tid = threadIdx.x;
  const int wave = tid >> 6, lane = tid & 63;
  const int wm = wave >> 1, wn = wave & 1;  // 2x2 wave grid, 64x64 each
  const int l15 = lane & 15, q4 = lane >> 4;
  const int bm0 = by * BM, bn0 = bx * BN;

  const bf16* Az = A + (long)blockIdx.z * sA;
  const bf16* Bz = B + (long)blockIdx.z * sB;
  CT* Cz = C + (long)blockIdx.z * sC;

  const int kg = (lane >> 3) & 7;        // k-granule (16 B)
  const int rl = wave * 8 + (lane & 7);  // row in 32-row quarter

  const bf16* apg = Az + (size_t)(bm0 + rl) * lda + kg * 8;
  const bf16* bpg = Bz + (size_t)(bn0 + rl) * ldb + kg * 8;
  const size_t la32 = (size_t)32 * lda, lb32 = (size_t)32 * ldb;
  short8* dstA = &As[kg * 128 + rl];
  short8* dstB = &Bs[kg * 128 + rl];

  const int Ke = (MODE == 3) ? min(K, (by + 1) * BM) : K;

  f32x4 acc[4][4] = {};
  short8 ra[4], rb[4];

#pragma unroll
  for (int j = 0; j < 4; j++) {
    ra[j] = *(const short8*)(apg + j * la32);
    rb[j] = *(const short8*)(bpg + j * lb32);
  }

  for (int k0 = 0; k0 < Ke; k0 += BK) {
    __syncthreads();
#pragma unroll
    for (int j = 0; j < 4; j++) {
      dstA[j * 32] = ra[j];  // vmcnt wait lands here, one compute-phase late
      dstB[j * 32] = rb[j];
    }
    __syncthreads();

    const int kn = k0 + BK;
    if (kn < Ke) {
#pragma unroll
      for (int j = 0; j < 4; j++) {
        ra[j] = *(const short8*)(apg + j * la32 + kn);
        rb[j] = *(const short8*)(bpg + j * lb32 + kn);
      }
    }

#pragma unroll
    for (int s = 0; s < 2; s++) {
      const int ch = (s * 4 + q4) * 128;
      short8 af[4], bfr[4];
#pragma unroll
      for (int i = 0; i < 4; i++)
        af[i] = As[ch + wm * 64 + i * 16 + l15];
#pragma unroll
      for (int j = 0; j < 4; j++)
        bfr[j] = Bs[ch + wn * 64 + j * 16 + l15];
#pragma unroll
      for (int i = 0; i < 4; i++)
#pragma unroll
        for (int j = 0; j < 4; j++)
          acc[i][j] = __builtin_amdgcn_mfma_f32_16x16x32_bf16(af[i], bfr[j], acc[i][j], 0, 0, 0);
    }
  }

  // epilogue: C/D layout col=lane&15, row=(lane>>4)*4+reg  [m89/m91 verified]
  if (MODE == 1 && bx >= 16) {
    // V block: write transposed into C2[D][MS]; pack r=0..3 (consec rows) 8 B
#pragma unroll
    for (int i = 0; i < 4; i++) {
#pragma unroll
      for (int j = 0; j < 4; j++) {
        const int rowb = bm0 + wm * 64 + i * 16 + q4 * 4;
        const int v = (bn0 - 2048) + wn * 64 + j * 16 + l15;
        bf16 t[4] = {__float2bfloat16(acc[i][j][0]), __float2bfloat16(acc[i][j][1]),
                     __float2bfloat16(acc[i][j][2]), __float2bfloat16(acc[i][j][3])};
        *(short4v*)(C2 + (size_t)v * MSZ + rowb) = *(short4v*)t;
      }
    }
    return;
  }

  CT* Cb = Cz;
  int coff = bn0;
  if (MODE == 1) {  // Q|K contiguous: K block sits MS*D after Q
    Cb = Cz + (bx >= 8 ? (size_t)MSZ * DD : 0);
    coff = (bx & 7) * BN;
  }
#pragma unroll
  for (int i = 0; i < 4; i++) {
#pragma unroll
    for (int j = 0; j < 4; j++) {
#pragma unroll
      for (int r = 0; r < 4; r++) {
        const int row = bm0 + wm * 64 + i * 16 + q4 * 4 + r;
        const int col = coff + wn * 64 + j * 16 + l15;
        cstore(&Cb[(size_t)row * ldc + col], acc[i][j][r] * scale);
      }
    }
  }
}

// Single-pass register softmax over the causal prefix; one 256-thr block per
// (q,b) row. Zeros above the diagonal so the PV GEMM needs no masking.
__global__ __launch_bounds__(256)
void softmax_rows(const bf16* __restrict__ Sc, bf16* __restrict__ P, int S) {
  const int q = blockIdx.x, b = blockIdx.y;
  const short8* srow = (const short8*)(Sc + ((size_t)b * S + q) * S);
  short8* prow = (short8*)(P + ((size_t)b * S + q) * S);
  const int len = q + 1;
  const int tid = threadIdx.x;
  const int wave = tid >> 6, lane = tid & 63;
  __shared__ float red[10];

  const short8 raw = srow[tid];
  float v[8];
#pragma unroll
  for (int j = 0; j < 8; j++) {
    const int k = tid * 8 + j;
    const float f = __bfloat162float(((const bf16*)&raw)[j]);
    v[j] = (k < len) ? f : -1e30f;
  }

  float m = v[0];
#pragma unroll
  for (int j = 1; j < 8; j++) m = fmaxf(m, v[j]);
#pragma unroll
  for (int o = 32; o; o >>= 1) m = fmaxf(m, __shfl_down(m, o));
  if (lane == 0) red[wave] = m;
  __syncthreads();
  if (tid == 0) red[8] = fmaxf(fmaxf(red[0], red[1]), fmaxf(red[2], red[3]));
  __syncthreads();
  const float M = red[8];

  float e[8], s = 0.f;
#pragma unroll
  for (int j = 0; j < 8; j++) { e[j] = __expf(v[j] - M); s += e[j]; }
#pragma unroll
  for (int o = 32; o; o >>= 1) s += __shfl_down(s, o);
  if (lane == 0) red[4 + wave] = s;
  __syncthreads();
  if (tid == 0) red[9] = red[4] + red[5] + red[6] + red[7];
  __syncthreads();
  const float inv = 1.f / red[9];

  short8 outp;
#pragma unroll
  for (int j = 0; j < 8; j++) {
    const int k = tid * 8 + j;
    ((bf16*)&outp)[j] = __float2bfloat16((k < len) ? e[j] * inv : 0.f);
  }
  prow[tid] = outp;
}

extern "C" void kernel_launch(void* const* d_in, const int* in_sizes, int n_in,
                              void* d_out, int out_size, void* d_ws, size_t ws_size,
                              hipStream_t stream) {
  const float* x  = (const float*)d_in[0];
  const float* Wq = (const float*)d_in[1];
  const float* Wk = (const float*)d_in[2];
  const float* Wv = (const float*)d_in[3];
  float* out = (float*)d_out;

  const int Bb = 4, S = 2048, D = 1024, MS = Bb * S;  // MS = 8192

  // ws layout; P aliases dead xb/W/Q region (consumed before softmax).
  char* ws = (char*)d_ws;
  bf16* xb = (bf16*)ws;                                          // 16.78 MB
  bf16* wb = (bf16*)(ws + (size_t)MS * D * 2);                   // 6.3 MB
  bf16* Q  = (bf16*)(ws + (size_t)MS * D * 2 + 3u * D * D * 2);  // 16.78 MB
  bf16* Kp = Q + (size_t)MS * D;                                 // 16.78 MB (contig after Q)
  bf16* VT = Kp + (size_t)MS * D;                                // 16.78 MB [D,MS]
  bf16* Sc = VT + (size_t)MS * D;                                // 33.55 MB [B,S,S]
  bf16* P  = (bf16*)ws;                                          // aliases xb/W/Q
  (void)Kp;

  dim3 blk(256);

  f2b<<<dim3(MS * D / 4 / 256), blk, 0, stream>>>(x, xb, MS * D);
  f2b3<<<dim3(D * D / 4 / 256, 3), blk, 0, stream>>>(Wq, Wk, Wv, wb, D * D);

  // QKV fused: [Q|K] rows + V transposed, one dispatch (24x64 blocks)
  gemm_bt<1, bf16><<<dim3(3 * D / BN, MS / BM, 1), blk, 0, stream>>>(
      xb, wb, Q, VT, D, D, D, D, 0, 0, 0, 1.f);
  // Sc = (Q K^T)/32, compact triangular grid: 136 tiles x 4 batches
  gemm_bt<2, bf16><<<dim3(136, 1, Bb), blk, 0, stream>>>(
      Q, Kp, Sc, nullptr, D, D, S, D,
      (long)S * D, (long)S * D, (long)S * S, 0.03125f);
  // P = row-softmax(Sc)
  softmax_rows<<<dim3(S, Bb), blk, 0, stream>>>(Sc, P, S);
  // out = P @ V  (B = VT batch slice, K clipped at diagonal)
  gemm_bt<3, float><<<dim3(D / BN, S / BM, Bb), blk, 0, stream>>>(
      P, VT, out, nullptr, S, MS, D, S,
      (long)S * S, (long)S, (long)S * D, 1.f);
}